// Round 2
// baseline (318.085 us; speedup 1.0000x reference)
//
#include <hip/hip_runtime.h>
#include <math.h>

constexpr int H  = 48;
constexpr int W  = 84;
constexpr int HW = H * W;      // 4032
constexpr int C  = 64;
constexpr int CQ = 32;
constexpr int QH = 192;
constexpr int QW = 336;
constexpr int NREF = 3;

typedef short bf16x8 __attribute__((ext_vector_type(8)));
typedef float f32x4  __attribute__((ext_vector_type(4)));

#define DEV __device__ __forceinline__

DEV unsigned short f2bf_rn(float f) {
  unsigned int u = __builtin_bit_cast(unsigned int, f);
  u += 0x7FFFu + ((u >> 16) & 1u);
  return (unsigned short)(u >> 16);
}
DEV float bf2f(unsigned short h) {
  unsigned int u = ((unsigned int)h) << 16;
  return __builtin_bit_cast(float, u);
}

DEV float dot64(const float* __restrict__ a, const float* __restrict__ b) {
  float s = 0.f;
#pragma unroll
  for (int c = 0; c < 64; c += 4) {
    float4 av = *reinterpret_cast<const float4*>(a + c);
    float4 bv = *reinterpret_cast<const float4*>(b + c);
    s = fmaf(av.x, bv.x, s);
    s = fmaf(av.y, bv.y, s);
    s = fmaf(av.z, bv.z, s);
    s = fmaf(av.w, bv.w, s);
  }
  return s;
}

// Transpose to channel-last; also emit split-bf16 (hi + residual lo).
__global__ __launch_bounds__(256) void k_prep(const float* __restrict__ fr,
                                              const float* __restrict__ ft,
                                              float* __restrict__ frT,
                                              float* __restrict__ ftT,
                                              unsigned short* __restrict__ rbh,
                                              unsigned short* __restrict__ rbl,
                                              unsigned short* __restrict__ tbh,
                                              unsigned short* __restrict__ tbl) {
  __shared__ float lds[64][65];
  const int r = blockIdx.y;
  const float* src = (r < NREF) ? (fr + (size_t)r * C * HW) : ft;
  float* dstF          = (r < NREF) ? (frT + (size_t)r * HW * C) : ftT;
  unsigned short* dstH = (r < NREF) ? (rbh + (size_t)r * HW * C) : tbh;
  unsigned short* dstL = (r < NREF) ? (rbl + (size_t)r * HW * C) : tbl;
  const int pb = blockIdx.x * 64;
  const int a = threadIdx.x & 63, b = threadIdx.x >> 6;
#pragma unroll
  for (int i = 0; i < 16; i++) {
    int c = i * 4 + b;
    lds[c][a] = src[c * HW + pb + a];
  }
  __syncthreads();
#pragma unroll
  for (int i = 0; i < 16; i++) {
    int p = i * 4 + b;
    float v = lds[a][p];
    int o = (pb + p) * C + a;
    dstF[o] = v;
    unsigned short h = f2bf_rn(v);
    dstH[o] = h;
    dstL[o] = f2bf_rn(v - bf2f(h));
  }
}

// Gather quantized_r[:, :, ::4, ::4] into dense channel-last [k][y][x][c].
__global__ __launch_bounds__(256) void k_qr(const float* __restrict__ q,
                                            float* __restrict__ qrdT) {
  const int yq = blockIdx.x, k = blockIdx.y;
  const int c = threadIdx.x & 31;
  for (int x = threadIdx.x >> 5; x < W; x += 8) {
    qrdT[(size_t)((k * H + yq) * W + x) * CQ + c] =
        q[(size_t)((k * CQ + c) * QH + yq * 4) * QW + x * 4];
  }
}

// One block = 16-pixel x-tile of one row. Everything fused.
__global__ __launch_bounds__(256, 2) void k_fused(
    const float* __restrict__ frT, const float* __restrict__ ftT,
    const float* __restrict__ qrdT,
    const unsigned short* __restrict__ rbh, const unsigned short* __restrict__ rbl,
    const unsigned short* __restrict__ tbh, const unsigned short* __restrict__ tbl,
    const int* __restrict__ ridx, const int* __restrict__ curp,
    float* __restrict__ out) {

  const int x0 = blockIdx.x * 16;
  const int y  = blockIdx.y;
  const int tid = threadIdx.x;
  const int lane = tid & 63, wave = tid >> 6;

  __shared__ float uP[16 * 628];   // P_all (offsets) / C14 / Wb (time-shared)
  __shared__ float lg[16 * 507];   // logits, then unnormalized softmax weights
  __shared__ float tl2[16][64];    // fp32 t for the tile
  __shared__ float sOy[16], sOx[16], sWy[16], sWx[16], sInv[16];
  __shared__ int   sIY[16], sIX[16];
  __shared__ float part[256];

  const int cur = curp[0];
  bool srch[NREF];
  int  dd[NREF];
  int  ls = -1;
#pragma unroll
  for (int k = 0; k < NREF; k++) {
    const int g = cur - ridx[k];
    srch[k] = (g > 15);
    int d = g / 15 + 1;
    dd[k] = d > 4 ? 4 : d;
    if (srch[k]) ls = k;
  }

  // fp32 t tile
  for (int i = tid; i < 16 * 64; i += 256) {
    int px = i >> 6, c = i & 63;
    tl2[px][c] = (x0 + px < W) ? ftT[(size_t)(y * W + x0 + px) * C + c] : 0.f;
  }

  // A-fragments (split-bf16), shared across all MFMA stages
  const int fpx = lane & 15;            // A row / B col pixel index
  const int fko = (lane >> 4) * 8;      // k-offset within K-step
  const bool pValid = (x0 + fpx) < W;
  const int apix = pValid ? (y * W + x0 + fpx) : 0;
  const bf16x8 zf = {0, 0, 0, 0, 0, 0, 0, 0};
  bf16x8 ah0 = *reinterpret_cast<const bf16x8*>(tbh + (size_t)apix * C + fko);
  bf16x8 ah1 = *reinterpret_cast<const bf16x8*>(tbh + (size_t)apix * C + fko + 32);
  bf16x8 al0 = *reinterpret_cast<const bf16x8*>(tbl + (size_t)apix * C + fko);
  bf16x8 al1 = *reinterpret_cast<const bf16x8*>(tbl + (size_t)apix * C + fko + 32);
  if (!pValid) { ah0 = zf; ah1 = zf; al0 = zf; al1 = zf; }
  __syncthreads();

  // ================= per search ref: offsets + search logits =================
  for (int si = 0; si < NREF; ++si) {
    if (!srch[si]) continue;
    const int d = dd[si];
    const int Zoff = (d == 1) ? 16 : (d == 2) ? 32 : 48;
    const int NZT  = (d == 1) ? 3  : (d == 2) ? 5  : 7;
    const int Minv = (d == 1) ? 65536 : (d == 2) ? 32768 : (d == 3) ? 21846 : 16384;
    const unsigned short* rH = rbh + (size_t)si * HW * C;
    const unsigned short* rL = rbl + (size_t)si * HW * C;

    // --- 25x25 dilated correlation via banded MFMA ---
    for (int p = wave; p < 25; p += 4) {
      const int row2 = y + d * (p - 12);
      const bool rv = (row2 >= 0) && (row2 < H);
      for (int zt = 0; zt < NZT; ++zt) {
        const int z0 = x0 - Zoff + zt * 16;
        const int z = z0 + fpx;
        const bool bv = rv && (z >= 0) && (z < W);
        const int bpix = bv ? (row2 * W + z) : 0;
        bf16x8 bh0 = *reinterpret_cast<const bf16x8*>(rH + (size_t)bpix * C + fko);
        bf16x8 bh1 = *reinterpret_cast<const bf16x8*>(rH + (size_t)bpix * C + fko + 32);
        bf16x8 bl0 = *reinterpret_cast<const bf16x8*>(rL + (size_t)bpix * C + fko);
        bf16x8 bl1 = *reinterpret_cast<const bf16x8*>(rL + (size_t)bpix * C + fko + 32);
        if (!bv) { bh0 = zf; bh1 = zf; bl0 = zf; bl1 = zf; }
        f32x4 acc = {0.f, 0.f, 0.f, 0.f};
        acc = __builtin_amdgcn_mfma_f32_16x16x32_bf16(ah0, bh0, acc, 0, 0, 0);
        acc = __builtin_amdgcn_mfma_f32_16x16x32_bf16(ah1, bh1, acc, 0, 0, 0);
        acc = __builtin_amdgcn_mfma_f32_16x16x32_bf16(ah0, bl0, acc, 0, 0, 0);
        acc = __builtin_amdgcn_mfma_f32_16x16x32_bf16(ah1, bl1, acc, 0, 0, 0);
        acc = __builtin_amdgcn_mfma_f32_16x16x32_bf16(al0, bh0, acc, 0, 0, 0);
        acc = __builtin_amdgcn_mfma_f32_16x16x32_bf16(al1, bh1, acc, 0, 0, 0);
#pragma unroll
        for (int r = 0; r < 4; r++) {
          const int xl = (lane >> 4) * 4 + r;       // A row (pixel in tile)
          const int qnum = (z0 + fpx) - (x0 + xl) + 12 * d;
          if (qnum >= 0) {
            const int q = (qnum * Minv) >> 16;
            if (q * d == qnum && q < 25) uP[xl * 628 + p * 25 + q] = acc[r];
          }
        }
      }
    }
    __syncthreads();

    // --- per-pixel softmax over 625 -> expected offsets ---
    {
      const int px = tid >> 4, s = tid & 15;
      float m = -1e30f;
      for (int i = s; i < 625; i += 16) m = fmaxf(m, uP[px * 628 + i]);
#pragma unroll
      for (int o = 8; o > 0; o >>= 1) m = fmaxf(m, __shfl_xor(m, o, 64));
      float se = 0.f, sy = 0.f, sx = 0.f;
      for (int i = s; i < 625; i += 16) {
        const float e = expf(uP[px * 628 + i] - m);
        const int p = i / 25, q = i - p * 25;
        se += e; sy += e * (float)(p - 12); sx += e * (float)(q - 12);
      }
#pragma unroll
      for (int o = 8; o > 0; o >>= 1) {
        se += __shfl_xor(se, o, 64);
        sy += __shfl_xor(sy, o, 64);
        sx += __shfl_xor(sx, o, 64);
      }
      if (s == 0) {
        const float inv = 1.f / se;
        const float oy = (float)d * sy * inv, ox = (float)d * sx * inv;
        sOy[px] = oy; sOx[px] = ox;
        const float fy = (float)y + oy, fx = (float)(x0 + px) + ox;
        const float Y0 = floorf(fy), X0 = floorf(fx);
        sIY[px] = (int)Y0; sIX[px] = (int)X0;
        sWy[px] = fy - Y0; sWx[px] = fx - X0;
      }
    }
    __syncthreads();

    // --- search logits: 14x14 integer corr field, then 2x2 bilinear ---
    float* C14 = uP;  // [16][196]
    const float* frB = frT + (size_t)si * HW * C;
    for (int it = tid; it < 16 * 196; it += 256) {
      const int px = it / 196, ii = it - px * 196;
      const int i = ii / 14, j = ii - i * 14;
      const int row = sIY[px] + i - 6, col = sIX[px] + j - 6;
      float s = 0.f;
      if ((unsigned)row < (unsigned)H && (unsigned)col < (unsigned)W)
        s = dot64(tl2[px], frB + (size_t)(row * W + col) * C);
      C14[px * 196 + ii] = s;
    }
    __syncthreads();
    for (int it = tid; it < 16 * 169; it += 256) {
      const int px = it / 169, ii = it - px * 169;
      const int i = ii / 13, j = ii - i * 13;
      const float* cp = &C14[px * 196 + i * 14 + j];
      const float wy = sWy[px], wx = sWx[px];
      lg[px * 507 + si * 169 + ii] =
          (1.f - wy) * ((1.f - wx) * cp[0] + wx * cp[1]) +
          wy * ((1.f - wx) * cp[14] + wx * cp[15]);
    }
    __syncthreads();
  }

  // ================= unfold logits via banded MFMA (d=1, 13x13) =================
  for (int k = 0; k < NREF; k++) {
    if (srch[k]) continue;
    const unsigned short* rH = rbh + (size_t)k * HW * C;
    const unsigned short* rL = rbl + (size_t)k * HW * C;
    for (int dp = wave; dp < 13; dp += 4) {
      const int row2 = y + dp - 6;
      const bool rv = (row2 >= 0) && (row2 < H);
      for (int zt = 0; zt < 3; ++zt) {
        const int z0 = x0 - 16 + zt * 16;
        const int z = z0 + fpx;
        const bool bv = rv && (z >= 0) && (z < W);
        const int bpix = bv ? (row2 * W + z) : 0;
        bf16x8 bh0 = *reinterpret_cast<const bf16x8*>(rH + (size_t)bpix * C + fko);
        bf16x8 bh1 = *reinterpret_cast<const bf16x8*>(rH + (size_t)bpix * C + fko + 32);
        bf16x8 bl0 = *reinterpret_cast<const bf16x8*>(rL + (size_t)bpix * C + fko);
        bf16x8 bl1 = *reinterpret_cast<const bf16x8*>(rL + (size_t)bpix * C + fko + 32);
        if (!bv) { bh0 = zf; bh1 = zf; bl0 = zf; bl1 = zf; }
        f32x4 acc = {0.f, 0.f, 0.f, 0.f};
        acc = __builtin_amdgcn_mfma_f32_16x16x32_bf16(ah0, bh0, acc, 0, 0, 0);
        acc = __builtin_amdgcn_mfma_f32_16x16x32_bf16(ah1, bh1, acc, 0, 0, 0);
        acc = __builtin_amdgcn_mfma_f32_16x16x32_bf16(ah0, bl0, acc, 0, 0, 0);
        acc = __builtin_amdgcn_mfma_f32_16x16x32_bf16(ah1, bl1, acc, 0, 0, 0);
        acc = __builtin_amdgcn_mfma_f32_16x16x32_bf16(al0, bh0, acc, 0, 0, 0);
        acc = __builtin_amdgcn_mfma_f32_16x16x32_bf16(al1, bh1, acc, 0, 0, 0);
#pragma unroll
        for (int r = 0; r < 4; r++) {
          const int xl = (lane >> 4) * 4 + r;
          const int q = (z0 + fpx) - (x0 + xl) + 6;
          if (q >= 0 && q < 13) lg[xl * 507 + k * 169 + dp * 13 + q] = acc[r];
        }
      }
    }
  }
  __syncthreads();

  // ================= joint softmax over 507 =================
  {
    const int px = tid >> 4, s = tid & 15;
    float m = -1e30f;
    for (int i = s; i < 507; i += 16) m = fmaxf(m, lg[px * 507 + i]);
#pragma unroll
    for (int o = 8; o > 0; o >>= 1) m = fmaxf(m, __shfl_xor(m, o, 64));
    float se = 0.f;
    for (int i = s; i < 507; i += 16) {
      const float e = expf(lg[px * 507 + i] - m);
      lg[px * 507 + i] = e;
      se += e;
    }
#pragma unroll
    for (int o = 8; o > 0; o >>= 1) se += __shfl_xor(se, o, 64);
    if (s == 0) sInv[px] = 1.f / se;
  }
  __syncthreads();

  // ================= fused output gather =================
  const int c0 = tid & 31, g = tid >> 5;   // 8 groups x 32 channels
  float* Wb = uP;                          // [196]
  for (int px = 0; px < 16; ++px) {
    const int xg = x0 + px;
    float acc = 0.f;
    for (int k = 0; k < NREF; k++) {
      const float* qb = qrdT + (size_t)k * HW * CQ;
      if (srch[k]) {
        __syncthreads();   // protect Wb (and part) reuse
        const float wy = sWy[px], wx = sWx[px];
        const float* wk = &lg[px * 507 + k * 169];
        for (int it = tid; it < 196; it += 256) {
          const int i = it / 14, j = it - i * 14;
          const float a00 = (i < 13 && j < 13) ? wk[i * 13 + j] : 0.f;
          const float a01 = (i < 13 && j >= 1) ? wk[i * 13 + j - 1] : 0.f;
          const float a10 = (i >= 1 && j < 13) ? wk[(i - 1) * 13 + j] : 0.f;
          const float a11 = (i >= 1 && j >= 1) ? wk[(i - 1) * 13 + j - 1] : 0.f;
          Wb[it] = (1.f - wy) * ((1.f - wx) * a00 + wx * a01) +
                   wy * ((1.f - wx) * a10 + wx * a11);
        }
        __syncthreads();
        for (int it = g; it < 196; it += 8) {
          const int i = it / 14, j = it - i * 14;
          const int row = sIY[px] + i - 6, col = sIX[px] + j - 6;
          if ((unsigned)row < (unsigned)H && (unsigned)col < (unsigned)W)
            acc += Wb[it] * qb[(size_t)(row * W + col) * CQ + c0];
        }
      } else {
        const float* wk = &lg[px * 507 + k * 169];
        for (int it = g; it < 169; it += 8) {
          const int p = it / 13, q = it - p * 13;
          const int row = y + p - 6, col = xg + q - 6;
          if ((unsigned)row < (unsigned)H && (unsigned)col < (unsigned)W)
            acc += wk[it] * qb[(size_t)(row * W + col) * CQ + c0];
        }
      }
    }
    part[tid] = acc * sInv[px];
    __syncthreads();
    if (tid < 32) {
      float s2 = 0.f;
#pragma unroll
      for (int gg = 0; gg < 8; gg++) s2 += part[gg * 32 + tid];
      if (xg < W) out[(size_t)tid * HW + y * W + xg] = s2;
    }
    __syncthreads();
  }
}

extern "C" void kernel_launch(void* const* d_in, const int* in_sizes, int n_in,
                              void* d_out, int out_size, void* d_ws, size_t ws_size,
                              hipStream_t stream) {
  (void)in_sizes; (void)n_in; (void)out_size; (void)ws_size;
  const float* fr = (const float*)d_in[0];   // feats_r      (3,1,64,48,84)
  const float* ft = (const float*)d_in[1];   // feats_t      (1,64,48,84)
  const float* q  = (const float*)d_in[2];   // quantized_r  (3,1,32,192,336)
  const int* ridx = (const int*)d_in[3];     // ref_index    (3,)
  const int* cur  = (const int*)d_in[4];     // current_ind  (1,)
  float* out = (float*)d_out;

  char* ws = (char*)d_ws;
  float* frT  = (float*)ws;                                  ws += (size_t)NREF * HW * C * 4;
  float* ftT  = (float*)ws;                                  ws += (size_t)HW * C * 4;
  float* qrdT = (float*)ws;                                  ws += (size_t)NREF * HW * CQ * 4;
  unsigned short* rbh = (unsigned short*)ws;                 ws += (size_t)NREF * HW * C * 2;
  unsigned short* rbl = (unsigned short*)ws;                 ws += (size_t)NREF * HW * C * 2;
  unsigned short* tbh = (unsigned short*)ws;                 ws += (size_t)HW * C * 2;
  unsigned short* tbl = (unsigned short*)ws;                 ws += (size_t)HW * C * 2;

  k_prep<<<dim3(HW / 64, NREF + 1), dim3(256), 0, stream>>>(fr, ft, frT, ftT,
                                                            rbh, rbl, tbh, tbl);
  k_qr<<<dim3(H, NREF), dim3(256), 0, stream>>>(q, qrdT);
  k_fused<<<dim3(6, H), dim3(256), 0, stream>>>(frT, ftT, qrdT, rbh, rbl, tbh, tbl,
                                                ridx, cur, out);
}

// Round 3
// 97.683 us; speedup vs baseline: 3.2563x; 3.2563x over previous
//
#include <hip/hip_runtime.h>
#include <math.h>

constexpr int H  = 48;
constexpr int W  = 84;
constexpr int HW = H * W;      // 4032
constexpr int C  = 64;
constexpr int CQ = 32;
constexpr int QH = 192;
constexpr int QW = 336;
constexpr int NREF = 3;

typedef short bf16x8 __attribute__((ext_vector_type(8)));
typedef float f32x4  __attribute__((ext_vector_type(4)));

#define DEV __device__ __forceinline__

DEV unsigned short f2bf_rn(float f) {
  unsigned int u = __builtin_bit_cast(unsigned int, f);
  u += 0x7FFFu + ((u >> 16) & 1u);
  return (unsigned short)(u >> 16);
}
DEV float bf2f(unsigned short h) {
  unsigned int u = ((unsigned int)h) << 16;
  return __builtin_bit_cast(float, u);
}

DEV float block_sum(float v, float* red) {
  __syncthreads();
#pragma unroll
  for (int o = 32; o > 0; o >>= 1) v += __shfl_down(v, o, 64);
  if ((threadIdx.x & 63) == 0) red[threadIdx.x >> 6] = v;
  __syncthreads();
  return red[0] + red[1] + red[2] + red[3];
}
DEV float block_max(float v, float* red) {
  __syncthreads();
#pragma unroll
  for (int o = 32; o > 0; o >>= 1) v = fmaxf(v, __shfl_down(v, o, 64));
  if ((threadIdx.x & 63) == 0) red[threadIdx.x >> 6] = v;
  __syncthreads();
  return fmaxf(fmaxf(red[0], red[1]), fmaxf(red[2], red[3]));
}

// Transpose to channel-last; also emit split-bf16 (hi + residual lo).
__global__ __launch_bounds__(256) void k_prep(const float* __restrict__ fr,
                                              const float* __restrict__ ft,
                                              float* __restrict__ frT,
                                              float* __restrict__ ftT,
                                              unsigned short* __restrict__ rbh,
                                              unsigned short* __restrict__ rbl,
                                              unsigned short* __restrict__ tbh,
                                              unsigned short* __restrict__ tbl) {
  __shared__ float lds[64][65];
  const int r = blockIdx.y;
  const float* src = (r < NREF) ? (fr + (size_t)r * C * HW) : ft;
  float* dstF          = (r < NREF) ? (frT + (size_t)r * HW * C) : ftT;
  unsigned short* dstH = (r < NREF) ? (rbh + (size_t)r * HW * C) : tbh;
  unsigned short* dstL = (r < NREF) ? (rbl + (size_t)r * HW * C) : tbl;
  const int pb = blockIdx.x * 64;
  const int a = threadIdx.x & 63, b = threadIdx.x >> 6;
#pragma unroll
  for (int i = 0; i < 16; i++) {
    int c = i * 4 + b;
    lds[c][a] = src[c * HW + pb + a];
  }
  __syncthreads();
#pragma unroll
  for (int i = 0; i < 16; i++) {
    int p = i * 4 + b;
    float v = lds[a][p];
    int o = (pb + p) * C + a;
    dstF[o] = v;
    unsigned short h = f2bf_rn(v);
    dstH[o] = h;
    dstL[o] = f2bf_rn(v - bf2f(h));
  }
}

// Gather quantized_r[:, :, ::4, ::4] into dense channel-last [k][y][x][c].
__global__ __launch_bounds__(256) void k_qr(const float* __restrict__ q,
                                            float* __restrict__ qrdT) {
  const int yq = blockIdx.x, k = blockIdx.y;
  const int c = threadIdx.x & 31;
  for (int x = threadIdx.x >> 5; x < W; x += 8) {
    qrdT[(size_t)((k * H + yq) * W + x) * CQ + c] =
        q[(size_t)((k * CQ + c) * QH + yq * 4) * QW + x * 4];
  }
}

__global__ __launch_bounds__(256) void k_zero(float* __restrict__ p, int n) {
  int i = blockIdx.x * 256 + threadIdx.x;
  if (i < n) p[i] = 0.f;
}

DEV f32x4 band_mfma(bf16x8 ah0, bf16x8 ah1, bf16x8 al0, bf16x8 al1,
                    const unsigned short* __restrict__ rH,
                    const unsigned short* __restrict__ rL,
                    int bpix, int fko, bool bv) {
  const bf16x8 zf = {0, 0, 0, 0, 0, 0, 0, 0};
  bf16x8 bh0 = *reinterpret_cast<const bf16x8*>(rH + (size_t)bpix * C + fko);
  bf16x8 bh1 = *reinterpret_cast<const bf16x8*>(rH + (size_t)bpix * C + fko + 32);
  bf16x8 bl0 = *reinterpret_cast<const bf16x8*>(rL + (size_t)bpix * C + fko);
  bf16x8 bl1 = *reinterpret_cast<const bf16x8*>(rL + (size_t)bpix * C + fko + 32);
  if (!bv) { bh0 = zf; bh1 = zf; bl0 = zf; bl1 = zf; }
  f32x4 acc = {0.f, 0.f, 0.f, 0.f};
  acc = __builtin_amdgcn_mfma_f32_16x16x32_bf16(ah0, bh0, acc, 0, 0, 0);
  acc = __builtin_amdgcn_mfma_f32_16x16x32_bf16(ah1, bh1, acc, 0, 0, 0);
  acc = __builtin_amdgcn_mfma_f32_16x16x32_bf16(ah0, bl0, acc, 0, 0, 0);
  acc = __builtin_amdgcn_mfma_f32_16x16x32_bf16(ah1, bl1, acc, 0, 0, 0);
  acc = __builtin_amdgcn_mfma_f32_16x16x32_bf16(al0, bh0, acc, 0, 0, 0);
  acc = __builtin_amdgcn_mfma_f32_16x16x32_bf16(al1, bh1, acc, 0, 0, 0);
  return acc;
}

// 25x25 dilated correlation, banded MFMA; reduces exp-partials into per-pixel
// atomics (se, sum e*(p-12), sum e*(q-12)). One wave per (xtile, y, si, p).
__global__ __launch_bounds__(64) void k_corr625(
    const unsigned short* __restrict__ rbh, const unsigned short* __restrict__ rbl,
    const unsigned short* __restrict__ tbh, const unsigned short* __restrict__ tbl,
    const int* __restrict__ ridx, const int* __restrict__ curp,
    float* __restrict__ accum) {
  const int si = blockIdx.z / 25, p = blockIdx.z % 25;
  const int gap = curp[0] - ridx[si];
  if (gap <= 15) return;
  int d = gap / 15 + 1; if (d > 4) d = 4;

  const int y = blockIdx.y, x0 = blockIdx.x * 16;
  const int lane = threadIdx.x;
  const int fpx = lane & 15, fko = (lane >> 4) * 8;

  const int Zoff = (d == 1) ? 16 : (d == 2) ? 32 : 48;
  const int NZT  = (d == 1) ? 3  : (d == 2) ? 5  : 7;
  const int Minv = (d == 1) ? 65536 : (d == 2) ? 32768 : (d == 3) ? 21846 : 16384;

  const bool pValid = (x0 + fpx) < W;
  const int apix = pValid ? (y * W + x0 + fpx) : 0;
  const bf16x8 zf = {0, 0, 0, 0, 0, 0, 0, 0};
  bf16x8 ah0 = *reinterpret_cast<const bf16x8*>(tbh + (size_t)apix * C + fko);
  bf16x8 ah1 = *reinterpret_cast<const bf16x8*>(tbh + (size_t)apix * C + fko + 32);
  bf16x8 al0 = *reinterpret_cast<const bf16x8*>(tbl + (size_t)apix * C + fko);
  bf16x8 al1 = *reinterpret_cast<const bf16x8*>(tbl + (size_t)apix * C + fko + 32);
  if (!pValid) { ah0 = zf; ah1 = zf; al0 = zf; al1 = zf; }

  const int row2 = y + d * (p - 12);
  const bool rv = (row2 >= 0) && (row2 < H);
  const unsigned short* rH = rbh + (size_t)si * HW * C;
  const unsigned short* rL = rbl + (size_t)si * HW * C;

  float se[4] = {0.f, 0.f, 0.f, 0.f};
  float sq[4] = {0.f, 0.f, 0.f, 0.f};

  for (int zt = 0; zt < NZT; ++zt) {
    const int z0 = x0 - Zoff + zt * 16;
    const int z = z0 + fpx;
    const bool bv = rv && (z >= 0) && (z < W);
    const int bpix = bv ? (row2 * W + z) : 0;
    f32x4 acc = band_mfma(ah0, ah1, al0, al1, rH, rL, bpix, fko, bv);
#pragma unroll
    for (int r = 0; r < 4; r++) {
      const int xl = (lane >> 4) * 4 + r;
      const int qnum = (z0 + fpx) - (x0 + xl) + 12 * d;
      if (qnum >= 0) {
        const int q = (qnum * Minv) >> 16;
        if (q * d == qnum && q < 25) {
          const float e = __expf(fminf(acc[r], 60.f));
          se[r] += e;
          sq[r] += e * (float)(q - 12);
        }
      }
    }
  }

  // reduce over the 16 B-col lanes (same xl), then one atomic set per pixel
#pragma unroll
  for (int r = 0; r < 4; r++) {
#pragma unroll
    for (int o = 1; o < 16; o <<= 1) {
      se[r] += __shfl_xor(se[r], o, 64);
      sq[r] += __shfl_xor(sq[r], o, 64);
    }
  }
  if (fpx == 0) {
#pragma unroll
    for (int r = 0; r < 4; r++) {
      const int xl = (lane >> 4) * 4 + r;
      if (x0 + xl < W) {
        float* a = accum + (size_t)(si * HW + y * W + x0 + xl) * 3;
        atomicAdd(a + 0, se[r]);
        atomicAdd(a + 1, se[r] * (float)(p - 12));
        atomicAdd(a + 2, sq[r]);
      }
    }
  }
}

// Unfold (d=1, 13x13) logits via banded MFMA -> lg[pix][507..512 layout].
__global__ __launch_bounds__(64) void k_unfold(
    const unsigned short* __restrict__ rbh, const unsigned short* __restrict__ rbl,
    const unsigned short* __restrict__ tbh, const unsigned short* __restrict__ tbl,
    const int* __restrict__ ridx, const int* __restrict__ curp,
    float* __restrict__ lg) {
  const int k = blockIdx.z / 13, dp = blockIdx.z % 13;
  const int gap = curp[0] - ridx[k];
  if (gap > 15) return;                       // search refs handled elsewhere

  const int y = blockIdx.y, x0 = blockIdx.x * 16;
  const int lane = threadIdx.x;
  const int fpx = lane & 15, fko = (lane >> 4) * 8;

  const bool pValid = (x0 + fpx) < W;
  const int apix = pValid ? (y * W + x0 + fpx) : 0;
  const bf16x8 zf = {0, 0, 0, 0, 0, 0, 0, 0};
  bf16x8 ah0 = *reinterpret_cast<const bf16x8*>(tbh + (size_t)apix * C + fko);
  bf16x8 ah1 = *reinterpret_cast<const bf16x8*>(tbh + (size_t)apix * C + fko + 32);
  bf16x8 al0 = *reinterpret_cast<const bf16x8*>(tbl + (size_t)apix * C + fko);
  bf16x8 al1 = *reinterpret_cast<const bf16x8*>(tbl + (size_t)apix * C + fko + 32);
  if (!pValid) { ah0 = zf; ah1 = zf; al0 = zf; al1 = zf; }

  const int row2 = y + dp - 6;
  const bool rv = (row2 >= 0) && (row2 < H);
  const unsigned short* rH = rbh + (size_t)k * HW * C;
  const unsigned short* rL = rbl + (size_t)k * HW * C;

  for (int zt = 0; zt < 3; ++zt) {
    const int z0 = x0 - 16 + zt * 16;
    const int z = z0 + fpx;
    const bool bv = rv && (z >= 0) && (z < W);
    const int bpix = bv ? (row2 * W + z) : 0;
    f32x4 acc = band_mfma(ah0, ah1, al0, al1, rH, rL, bpix, fko, bv);
#pragma unroll
    for (int r = 0; r < 4; r++) {
      const int xl = (lane >> 4) * 4 + r;
      const int q = (z0 + fpx) - (x0 + xl) + 6;
      if (q >= 0 && q < 13 && (x0 + xl) < W)
        lg[(size_t)(y * W + x0 + xl) * 512 + k * 169 + dp * 13 + q] = acc[r];
    }
  }
}

// Per (pixel, search ref): offsets from accums, 14x14 field via contiguous
// cooperative row loads, bilinear -> lg. Also persists sample params.
__global__ __launch_bounds__(256) void k_search(
    const float* __restrict__ frT, const float* __restrict__ ftT,
    const int* __restrict__ ridx, const int* __restrict__ curp,
    const float* __restrict__ accum, float* __restrict__ samp,
    float* __restrict__ lg) {
  const int si = blockIdx.y;
  const int gap = curp[0] - ridx[si];
  if (gap <= 15) return;
  int d = gap / 15 + 1; if (d > 4) d = 4;

  const int pix = blockIdx.x;
  const int y = pix / W, x = pix - y * W;
  const int tid = threadIdx.x;

  __shared__ __align__(16) float tl[64];
  __shared__ float C14[14][16];
  __shared__ float sP[4];

  if (tid < 64) tl[tid] = ftT[(size_t)pix * C + tid];
  if (tid == 0) {
    const float* a = accum + (size_t)(si * HW + pix) * 3;
    const float inv = 1.f / a[0];
    const float oy = (float)d * a[1] * inv, ox = (float)d * a[2] * inv;
    const float fy = (float)y + oy, fx = (float)x + ox;
    const float Y0 = floorf(fy), X0 = floorf(fx);
    sP[0] = Y0; sP[1] = X0; sP[2] = fy - Y0; sP[3] = fx - X0;
    *reinterpret_cast<float4*>(samp + (size_t)(si * HW + pix) * 4) =
        make_float4(Y0, X0, fy - Y0, fx - X0);
  }
  __syncthreads();

  const int iY = (int)sP[0], iX = (int)sP[1];
  const float wy = sP[2], wx = sP[3];
  const float* frB = frT + (size_t)si * HW * C;

  if (tid < 224) {
    const int j = tid >> 4, cg = tid & 15;
    const int col = iX - 6 + j;
    const bool cv = (col >= 0) && (col < W);
    const float4 tv = *reinterpret_cast<const float4*>(&tl[cg * 4]);
#pragma unroll 2
    for (int i = 0; i < 14; ++i) {
      const int row = iY - 6 + i;
      float s = 0.f;
      if (cv && row >= 0 && row < H) {
        const float4 rv4 = *reinterpret_cast<const float4*>(
            frB + (size_t)(row * W + col) * C + cg * 4);
        s = tv.x * rv4.x + tv.y * rv4.y + tv.z * rv4.z + tv.w * rv4.w;
      }
      s += __shfl_xor(s, 1, 64);
      s += __shfl_xor(s, 2, 64);
      s += __shfl_xor(s, 4, 64);
      s += __shfl_xor(s, 8, 64);
      if (cg == 0) C14[i][j] = s;
    }
  }
  __syncthreads();

  for (int it = tid; it < 169; it += 256) {
    const int i = it / 13, j = it - i * 13;
    const float v = (1.f - wy) * ((1.f - wx) * C14[i][j] + wx * C14[i][j + 1]) +
                    wy * ((1.f - wx) * C14[i + 1][j] + wx * C14[i + 1][j + 1]);
    lg[(size_t)pix * 512 + si * 169 + it] = v;
  }
}

// Per pixel: joint softmax over 507 + fused weighted gather of qrdT.
__global__ __launch_bounds__(256) void k_final(
    const float* __restrict__ qrdT, const int* __restrict__ ridx,
    const int* __restrict__ curp, const float* __restrict__ samp,
    const float* __restrict__ lg, float* __restrict__ out) {
  const int pix = blockIdx.x;
  const int y = pix / W, x = pix - y * W;
  const int tid = threadIdx.x;
  const int lane = tid & 63, wave = tid >> 6;

  __shared__ __align__(16) float wlg[512];
  __shared__ int   wloc[608];
  __shared__ float wval[608];
  __shared__ float red[4];
  __shared__ float part[4][32];
  __shared__ __align__(16) float sI[4];

  const int cur = curp[0];
  bool srch[NREF];
  int ls = -1;
#pragma unroll
  for (int k = 0; k < NREF; k++) {
    srch[k] = (cur - ridx[k]) > 15;
    if (srch[k]) ls = k;
  }

  for (int i = tid; i < 127; i += 256)
    *reinterpret_cast<float4*>(&wlg[i * 4]) =
        *reinterpret_cast<const float4*>(lg + (size_t)pix * 512 + i * 4);
  if (tid == 0 && ls >= 0)
    *reinterpret_cast<float4*>(sI) =
        *reinterpret_cast<const float4*>(samp + (size_t)(ls * HW + pix) * 4);
  __syncthreads();

  float m = -1e30f;
  for (int i = tid; i < 507; i += 256) m = fmaxf(m, wlg[i]);
  m = block_max(m, red);
  float se = 0.f;
  for (int i = tid; i < 507; i += 256) {
    const float e = __expf(wlg[i] - m);
    wlg[i] = e;
    se += e;
  }
  se = block_sum(se, red);
  const float inv = 1.f / se;

  int liY = 0, liX = 0; float lwy = 0.f, lwx = 0.f;
  if (ls >= 0) { liY = (int)sI[0]; liX = (int)sI[1]; lwy = sI[2]; lwx = sI[3]; }
  __syncthreads();   // wlg fully exp'd before list build

  for (int k = 0; k < NREF; k++) {
    const int base = k * 196;
    if (srch[k]) {
      const float* wk = &wlg[k * 169];
      for (int it = tid; it < 196; it += 256) {
        const int i = it / 14, j = it - i * 14;
        const float a00 = (i < 13 && j < 13) ? wk[i * 13 + j] : 0.f;
        const float a01 = (i < 13 && j >= 1) ? wk[i * 13 + j - 1] : 0.f;
        const float a10 = (i >= 1 && j < 13) ? wk[(i - 1) * 13 + j] : 0.f;
        const float a11 = (i >= 1 && j >= 1) ? wk[(i - 1) * 13 + j - 1] : 0.f;
        const float wv = (1.f - lwy) * ((1.f - lwx) * a00 + lwx * a01) +
                         lwy * ((1.f - lwx) * a10 + lwx * a11);
        const int row = liY + i - 6, col = liX + j - 6;
        const bool v = (unsigned)row < (unsigned)H && (unsigned)col < (unsigned)W;
        wloc[base + it] = v ? (k * HW + row * W + col) : 0;
        wval[base + it] = v ? wv : 0.f;
      }
    } else {
      for (int it = tid; it < 196; it += 256) {
        if (it < 169) {
          const int p = it / 13, q = it - p * 13;
          const int row = y + p - 6, col = x + q - 6;
          const bool v = (unsigned)row < (unsigned)H && (unsigned)col < (unsigned)W;
          wloc[base + it] = v ? (k * HW + row * W + col) : 0;
          wval[base + it] = v ? wlg[k * 169 + it] : 0.f;
        } else {
          wloc[base + it] = 0;
          wval[base + it] = 0.f;
        }
      }
    }
  }
  if (tid < 20) { wloc[588 + tid] = 0; wval[588 + tid] = 0.f; }
  __syncthreads();

  // gather: 8 lanes per location, float4 channels per lane
  const int c8 = lane & 7, l8 = lane >> 3;
  float a0 = 0.f, a1 = 0.f, a2 = 0.f, a3 = 0.f;
#pragma unroll 4
  for (int t = 0; t < 19; ++t) {
    const int e = t * 32 + wave * 8 + l8;
    const float wv = wval[e];
    const int loc = wloc[e];
    const float4 qv = *reinterpret_cast<const float4*>(
        qrdT + (size_t)loc * CQ + c8 * 4);
    a0 = fmaf(wv, qv.x, a0);
    a1 = fmaf(wv, qv.y, a1);
    a2 = fmaf(wv, qv.z, a2);
    a3 = fmaf(wv, qv.w, a3);
  }
#pragma unroll
  for (int o = 8; o < 64; o <<= 1) {
    a0 += __shfl_xor(a0, o, 64);
    a1 += __shfl_xor(a1, o, 64);
    a2 += __shfl_xor(a2, o, 64);
    a3 += __shfl_xor(a3, o, 64);
  }
  if (l8 == 0) {
    part[wave][c8 * 4 + 0] = a0;
    part[wave][c8 * 4 + 1] = a1;
    part[wave][c8 * 4 + 2] = a2;
    part[wave][c8 * 4 + 3] = a3;
  }
  __syncthreads();
  if (tid < 32) {
    const float s = part[0][tid] + part[1][tid] + part[2][tid] + part[3][tid];
    out[(size_t)tid * HW + pix] = s * inv;
  }
}

extern "C" void kernel_launch(void* const* d_in, const int* in_sizes, int n_in,
                              void* d_out, int out_size, void* d_ws, size_t ws_size,
                              hipStream_t stream) {
  (void)in_sizes; (void)n_in; (void)out_size; (void)ws_size;
  const float* fr = (const float*)d_in[0];   // feats_r      (3,1,64,48,84)
  const float* ft = (const float*)d_in[1];   // feats_t      (1,64,48,84)
  const float* q  = (const float*)d_in[2];   // quantized_r  (3,1,32,192,336)
  const int* ridx = (const int*)d_in[3];     // ref_index    (3,)
  const int* cur  = (const int*)d_in[4];     // current_ind  (1,)
  float* out = (float*)d_out;

  char* ws = (char*)d_ws;
  float* frT  = (float*)ws;          ws += (size_t)NREF * HW * C * 4;
  float* ftT  = (float*)ws;          ws += (size_t)HW * C * 4;
  float* qrdT = (float*)ws;          ws += (size_t)NREF * HW * CQ * 4;
  unsigned short* rbh = (unsigned short*)ws;  ws += (size_t)NREF * HW * C * 2;
  unsigned short* rbl = (unsigned short*)ws;  ws += (size_t)NREF * HW * C * 2;
  unsigned short* tbh = (unsigned short*)ws;  ws += (size_t)HW * C * 2;
  unsigned short* tbl = (unsigned short*)ws;  ws += (size_t)HW * C * 2;
  float* lg    = (float*)ws;         ws += (size_t)HW * 512 * 4;
  float* accum = (float*)ws;         ws += (size_t)NREF * HW * 3 * 4;
  float* samp  = (float*)ws;         ws += (size_t)NREF * HW * 4 * 4;

  const int nacc = NREF * HW * 3;

  k_prep<<<dim3(HW / 64, NREF + 1), dim3(256), 0, stream>>>(fr, ft, frT, ftT,
                                                            rbh, rbl, tbh, tbl);
  k_qr<<<dim3(H, NREF), dim3(256), 0, stream>>>(q, qrdT);
  k_zero<<<dim3((nacc + 255) / 256), dim3(256), 0, stream>>>(accum, nacc);
  k_corr625<<<dim3(6, H, NREF * 25), dim3(64), 0, stream>>>(rbh, rbl, tbh, tbl,
                                                            ridx, cur, accum);
  k_unfold<<<dim3(6, H, NREF * 13), dim3(64), 0, stream>>>(rbh, rbl, tbh, tbl,
                                                           ridx, cur, lg);
  k_search<<<dim3(HW, NREF), dim3(256), 0, stream>>>(frT, ftT, ridx, cur,
                                                     accum, samp, lg);
  k_final<<<dim3(HW), dim3(256), 0, stream>>>(qrdT, ridx, cur, samp, lg, out);
}

// Round 4
// 81.856 us; speedup vs baseline: 3.8859x; 1.1934x over previous
//
#include <hip/hip_runtime.h>
#include <math.h>

constexpr int H  = 48;
constexpr int W  = 84;
constexpr int HW = H * W;      // 4032
constexpr int C  = 64;
constexpr int CQ = 32;
constexpr int QH = 192;
constexpr int QW = 336;
constexpr int NREF = 3;

typedef short bf16x8 __attribute__((ext_vector_type(8)));
typedef float f32x4  __attribute__((ext_vector_type(4)));

#define DEV __device__ __forceinline__

DEV unsigned short f2bf_rn(float f) {
  unsigned int u = __builtin_bit_cast(unsigned int, f);
  u += 0x7FFFu + ((u >> 16) & 1u);
  return (unsigned short)(u >> 16);
}
DEV float bf2f(unsigned short h) {
  unsigned int u = ((unsigned int)h) << 16;
  return __builtin_bit_cast(float, u);
}

DEV float block_sum(float v, float* red) {
  __syncthreads();
#pragma unroll
  for (int o = 32; o > 0; o >>= 1) v += __shfl_down(v, o, 64);
  if ((threadIdx.x & 63) == 0) red[threadIdx.x >> 6] = v;
  __syncthreads();
  return red[0] + red[1] + red[2] + red[3];
}
DEV float block_max(float v, float* red) {
  __syncthreads();
#pragma unroll
  for (int o = 32; o > 0; o >>= 1) v = fmaxf(v, __shfl_down(v, o, 64));
  if ((threadIdx.x & 63) == 0) red[threadIdx.x >> 6] = v;
  __syncthreads();
  return fmaxf(fmaxf(red[0], red[1]), fmaxf(red[2], red[3]));
}

// y<4: transpose feats to channel-last (fp32 + split-bf16).
// y in 4..6: gather quantized_r[:, :, ::4, ::4] -> bf16 channel-last.
// y==7: zero the accum buffer.
__global__ __launch_bounds__(256) void k_prep(const float* __restrict__ fr,
                                              const float* __restrict__ ft,
                                              const float* __restrict__ q,
                                              float* __restrict__ frT,
                                              float* __restrict__ ftT,
                                              unsigned short* __restrict__ rbh,
                                              unsigned short* __restrict__ rbl,
                                              unsigned short* __restrict__ tbh,
                                              unsigned short* __restrict__ tbl,
                                              unsigned short* __restrict__ qrb,
                                              float* __restrict__ accum) {
  const int mode = blockIdx.y;
  const int tid = threadIdx.x;

  if (mode < 4) {
    __shared__ float lds[64][65];
    const int r = mode;
    const float* src = (r < NREF) ? (fr + (size_t)r * C * HW) : ft;
    float* dstF          = (r < NREF) ? (frT + (size_t)r * HW * C) : ftT;
    unsigned short* dstH = (r < NREF) ? (rbh + (size_t)r * HW * C) : tbh;
    unsigned short* dstL = (r < NREF) ? (rbl + (size_t)r * HW * C) : tbl;
    const int pb = blockIdx.x * 64;
    const int a = tid & 63, b = tid >> 6;
#pragma unroll
    for (int i = 0; i < 16; i++) {
      int c = i * 4 + b;
      lds[c][a] = src[c * HW + pb + a];
    }
    __syncthreads();
#pragma unroll
    for (int i = 0; i < 16; i++) {
      int p = i * 4 + b;
      float v = lds[a][p];
      int o = (pb + p) * C + a;
      dstF[o] = v;
      unsigned short h = f2bf_rn(v);
      dstH[o] = h;
      dstL[o] = f2bf_rn(v - bf2f(h));
    }
  } else if (mode < 7) {
    const int k = mode - 4;
#pragma unroll
    for (int i = 0; i < 8; i++) {
      const int o = blockIdx.x * 2048 + i * 256 + tid;   // 63*2048 = 4032*32
      const int pix = o >> 5, c = o & 31;
      const int yq = pix / W, xq = pix - yq * W;
      const float v = q[(size_t)((k * CQ + c) * QH + yq * 4) * QW + xq * 4];
      qrb[(size_t)k * HW * CQ + o] = f2bf_rn(v);
    }
  } else {
    const int nacc = NREF * HW * 3;
    for (int i = blockIdx.x * 256 + tid; i < nacc; i += 63 * 256) accum[i] = 0.f;
  }
}

DEV f32x4 band_mfma(bf16x8 ah0, bf16x8 ah1, bf16x8 al0, bf16x8 al1,
                    const unsigned short* __restrict__ rH,
                    const unsigned short* __restrict__ rL,
                    int bpix, int fko, bool bv) {
  const bf16x8 zf = {0, 0, 0, 0, 0, 0, 0, 0};
  bf16x8 bh0 = *reinterpret_cast<const bf16x8*>(rH + (size_t)bpix * C + fko);
  bf16x8 bh1 = *reinterpret_cast<const bf16x8*>(rH + (size_t)bpix * C + fko + 32);
  bf16x8 bl0 = *reinterpret_cast<const bf16x8*>(rL + (size_t)bpix * C + fko);
  bf16x8 bl1 = *reinterpret_cast<const bf16x8*>(rL + (size_t)bpix * C + fko + 32);
  if (!bv) { bh0 = zf; bh1 = zf; bl0 = zf; bl1 = zf; }
  f32x4 acc = {0.f, 0.f, 0.f, 0.f};
  acc = __builtin_amdgcn_mfma_f32_16x16x32_bf16(ah0, bh0, acc, 0, 0, 0);
  acc = __builtin_amdgcn_mfma_f32_16x16x32_bf16(ah1, bh1, acc, 0, 0, 0);
  acc = __builtin_amdgcn_mfma_f32_16x16x32_bf16(ah0, bl0, acc, 0, 0, 0);
  acc = __builtin_amdgcn_mfma_f32_16x16x32_bf16(ah1, bl1, acc, 0, 0, 0);
  acc = __builtin_amdgcn_mfma_f32_16x16x32_bf16(al0, bh0, acc, 0, 0, 0);
  acc = __builtin_amdgcn_mfma_f32_16x16x32_bf16(al1, bh1, acc, 0, 0, 0);
  return acc;
}

// z = si*7 + pz. Search ref: wave handles corr row p = pz*4+wave (25 rows,
// exp-partials -> atomics). Non-search ref: wave handles unfold row
// dp = pz*4+wave (13 rows, raw logits -> lg). 4 independent waves, no barriers.
__global__ __launch_bounds__(256) void k_mfma(
    const unsigned short* __restrict__ rbh, const unsigned short* __restrict__ rbl,
    const unsigned short* __restrict__ tbh, const unsigned short* __restrict__ tbl,
    const int* __restrict__ ridx, const int* __restrict__ curp,
    float* __restrict__ accum, float* __restrict__ lg) {
  const int si = blockIdx.z / 7, pz = blockIdx.z % 7;
  const int gap = curp[0] - ridx[si];
  const bool isSearch = gap > 15;
  const int lane = threadIdx.x & 63, wave = threadIdx.x >> 6;
  const int sub = pz * 4 + wave;              // p (corr) or dp (unfold)
  if (isSearch) { if (sub >= 25) return; }
  else          { if (sub >= 13) return; }

  const int y = blockIdx.y, x0 = blockIdx.x * 16;
  const int fpx = lane & 15, fko = (lane >> 4) * 8;

  const bool pValid = (x0 + fpx) < W;
  const int apix = pValid ? (y * W + x0 + fpx) : 0;
  const bf16x8 zf = {0, 0, 0, 0, 0, 0, 0, 0};
  bf16x8 ah0 = *reinterpret_cast<const bf16x8*>(tbh + (size_t)apix * C + fko);
  bf16x8 ah1 = *reinterpret_cast<const bf16x8*>(tbh + (size_t)apix * C + fko + 32);
  bf16x8 al0 = *reinterpret_cast<const bf16x8*>(tbl + (size_t)apix * C + fko);
  bf16x8 al1 = *reinterpret_cast<const bf16x8*>(tbl + (size_t)apix * C + fko + 32);
  if (!pValid) { ah0 = zf; ah1 = zf; al0 = zf; al1 = zf; }

  const unsigned short* rH = rbh + (size_t)si * HW * C;
  const unsigned short* rL = rbl + (size_t)si * HW * C;

  if (isSearch) {
    int d = gap / 15 + 1; if (d > 4) d = 4;
    const int Zoff = (d == 1) ? 16 : (d == 2) ? 32 : 48;
    const int NZT  = (d == 1) ? 3  : (d == 2) ? 5  : 7;
    const int Minv = (d == 1) ? 65536 : (d == 2) ? 32768 : (d == 3) ? 21846 : 16384;
    const int p = sub;
    const int row2 = y + d * (p - 12);
    const bool rv = (row2 >= 0) && (row2 < H);

    float se[4] = {0.f, 0.f, 0.f, 0.f};
    float sq[4] = {0.f, 0.f, 0.f, 0.f};
    for (int zt = 0; zt < NZT; ++zt) {
      const int z0 = x0 - Zoff + zt * 16;
      const int z = z0 + fpx;
      const bool bv = rv && (z >= 0) && (z < W);
      const int bpix = bv ? (row2 * W + z) : 0;
      f32x4 acc = band_mfma(ah0, ah1, al0, al1, rH, rL, bpix, fko, bv);
#pragma unroll
      for (int r = 0; r < 4; r++) {
        const int xl = (lane >> 4) * 4 + r;
        const int qnum = (z0 + fpx) - (x0 + xl) + 12 * d;
        if (qnum >= 0) {
          const int qq = (qnum * Minv) >> 16;
          if (qq * d == qnum && qq < 25) {
            const float e = __expf(fminf(acc[r], 60.f));
            se[r] += e;
            sq[r] += e * (float)(qq - 12);
          }
        }
      }
    }
#pragma unroll
    for (int r = 0; r < 4; r++) {
#pragma unroll
      for (int o = 1; o < 16; o <<= 1) {
        se[r] += __shfl_xor(se[r], o, 64);
        sq[r] += __shfl_xor(sq[r], o, 64);
      }
    }
    if (fpx == 0) {
#pragma unroll
      for (int r = 0; r < 4; r++) {
        const int xl = (lane >> 4) * 4 + r;
        if (x0 + xl < W) {
          float* a = accum + (size_t)(si * HW + y * W + x0 + xl) * 3;
          atomicAdd(a + 0, se[r]);
          atomicAdd(a + 1, se[r] * (float)(p - 12));
          atomicAdd(a + 2, sq[r]);
        }
      }
    }
  } else {
    const int dp = sub;
    const int row2 = y + dp - 6;
    const bool rv = (row2 >= 0) && (row2 < H);
    for (int zt = 0; zt < 3; ++zt) {
      const int z0 = x0 - 16 + zt * 16;
      const int z = z0 + fpx;
      const bool bv = rv && (z >= 0) && (z < W);
      const int bpix = bv ? (row2 * W + z) : 0;
      f32x4 acc = band_mfma(ah0, ah1, al0, al1, rH, rL, bpix, fko, bv);
#pragma unroll
      for (int r = 0; r < 4; r++) {
        const int xl = (lane >> 4) * 4 + r;
        const int qq = (z0 + fpx) - (x0 + xl) + 6;
        if (qq >= 0 && qq < 13 && (x0 + xl) < W)
          lg[(size_t)(y * W + x0 + xl) * 512 + si * 169 + dp * 13 + qq] = acc[r];
      }
    }
  }
}

// Per pixel: offsets -> 14x14 field -> bilinear search logits; unfold logits
// from lg; joint softmax over 507; fused bf16 gather.
__global__ __launch_bounds__(256) void k_pix(
    const float* __restrict__ frT, const float* __restrict__ ftT,
    const unsigned short* __restrict__ qrb, const float* __restrict__ lg,
    const float* __restrict__ accum,
    const int* __restrict__ ridx, const int* __restrict__ curp,
    float* __restrict__ out) {
  const int pix = blockIdx.x;
  const int y = pix / W, x = pix - y * W;
  const int tid = threadIdx.x;
  const int lane = tid & 63, wave = tid >> 6;

  __shared__ __align__(16) float tl[64];
  __shared__ float C14[14][16];
  __shared__ float sP[4];
  __shared__ float sLs[4];
  __shared__ float lgs[512];
  __shared__ float red[4];
  __shared__ int   wloc[640];
  __shared__ float wval[640];
  __shared__ float part[4][32];

  const int cur = curp[0];
  bool srch[NREF];
  int dd[NREF];
  int ls = -1;
#pragma unroll
  for (int k = 0; k < NREF; k++) {
    const int g = cur - ridx[k];
    srch[k] = (g > 15);
    int d = g / 15 + 1;
    dd[k] = d > 4 ? 4 : d;
    if (srch[k]) ls = k;
  }

  if (tid < 64) tl[tid] = ftT[(size_t)pix * C + tid];
  __syncthreads();

  // ---- search refs: offsets + field + bilinear logits ----
  for (int si = 0; si < NREF; ++si) {
    if (!srch[si]) continue;
    if (tid == 0) {
      const float* a = accum + (size_t)(si * HW + pix) * 3;
      const float inv = 1.f / a[0];
      const float oy = (float)dd[si] * a[1] * inv, ox = (float)dd[si] * a[2] * inv;
      const float fy = (float)y + oy, fx = (float)x + ox;
      const float Y0 = floorf(fy), X0 = floorf(fx);
      sP[0] = Y0; sP[1] = X0; sP[2] = fy - Y0; sP[3] = fx - X0;
      if (si == ls) { sLs[0] = Y0; sLs[1] = X0; sLs[2] = fy - Y0; sLs[3] = fx - X0; }
    }
    __syncthreads();
    const int iY = (int)sP[0], iX = (int)sP[1];
    const float wy = sP[2], wx = sP[3];
    const float* frB = frT + (size_t)si * HW * C;

    if (tid < 224) {
      const int j = tid >> 4, cg = tid & 15;
      const int col = iX - 6 + j;
      const bool cv = (col >= 0) && (col < W);
      const float4 tv = *reinterpret_cast<const float4*>(&tl[cg * 4]);
#pragma unroll 2
      for (int i = 0; i < 14; ++i) {
        const int row = iY - 6 + i;
        float s = 0.f;
        if (cv && row >= 0 && row < H) {
          const float4 rv4 = *reinterpret_cast<const float4*>(
              frB + (size_t)(row * W + col) * C + cg * 4);
          s = tv.x * rv4.x + tv.y * rv4.y + tv.z * rv4.z + tv.w * rv4.w;
        }
        s += __shfl_xor(s, 1, 64);
        s += __shfl_xor(s, 2, 64);
        s += __shfl_xor(s, 4, 64);
        s += __shfl_xor(s, 8, 64);
        if (cg == 0) C14[i][j] = s;
      }
    }
    __syncthreads();
    for (int it = tid; it < 169; it += 256) {
      const int i = it / 13, j = it - i * 13;
      lgs[si * 169 + it] =
          (1.f - wy) * ((1.f - wx) * C14[i][j] + wx * C14[i][j + 1]) +
          wy * ((1.f - wx) * C14[i + 1][j] + wx * C14[i + 1][j + 1]);
    }
    __syncthreads();   // C14/sP reused by next search ref
  }

  // ---- unfold logits from global ----
  for (int k = 0; k < NREF; k++) {
    if (srch[k]) continue;
    for (int it = tid; it < 169; it += 256)
      lgs[k * 169 + it] = lg[(size_t)pix * 512 + k * 169 + it];
  }
  __syncthreads();

  // ---- joint softmax over 507 ----
  float m = -1e30f;
  for (int i = tid; i < 507; i += 256) m = fmaxf(m, lgs[i]);
  m = block_max(m, red);
  float se = 0.f;
  for (int i = tid; i < 507; i += 256) {
    const float e = __expf(lgs[i] - m);
    lgs[i] = e;
    se += e;
  }
  se = block_sum(se, red);
  const float inv = 1.f / se;

  // ---- build gather list (compact) ----
  int bases[NREF], tot = 0;
#pragma unroll
  for (int k = 0; k < NREF; k++) { bases[k] = tot; tot += srch[k] ? 196 : 169; }
  const int NT = (tot + 63) >> 6;

  int liY = 0, liX = 0; float lwy = 0.f, lwx = 0.f;
  if (ls >= 0) { liY = (int)sLs[0]; liX = (int)sLs[1]; lwy = sLs[2]; lwx = sLs[3]; }

  for (int k = 0; k < NREF; k++) {
    const int base = bases[k];
    if (srch[k]) {
      const float* wk = &lgs[k * 169];
      for (int it = tid; it < 196; it += 256) {
        const int i = it / 14, j = it - i * 14;
        const float a00 = (i < 13 && j < 13) ? wk[i * 13 + j] : 0.f;
        const float a01 = (i < 13 && j >= 1) ? wk[i * 13 + j - 1] : 0.f;
        const float a10 = (i >= 1 && j < 13) ? wk[(i - 1) * 13 + j] : 0.f;
        const float a11 = (i >= 1 && j >= 1) ? wk[(i - 1) * 13 + j - 1] : 0.f;
        const float wv = (1.f - lwy) * ((1.f - lwx) * a00 + lwx * a01) +
                         lwy * ((1.f - lwx) * a10 + lwx * a11);
        const int row = liY + i - 6, col = liX + j - 6;
        const bool v = (unsigned)row < (unsigned)H && (unsigned)col < (unsigned)W;
        wloc[base + it] = v ? (k * HW + row * W + col) : 0;
        wval[base + it] = v ? wv : 0.f;
      }
    } else {
      for (int it = tid; it < 169; it += 256) {
        const int p = it / 13, q = it - p * 13;
        const int row = y + p - 6, col = x + q - 6;
        const bool v = (unsigned)row < (unsigned)H && (unsigned)col < (unsigned)W;
        wloc[base + it] = v ? (k * HW + row * W + col) : 0;
        wval[base + it] = v ? lgs[k * 169 + it] : 0.f;
      }
    }
  }
  for (int e = tot + tid; e < NT * 64; e += 256) { wloc[e] = 0; wval[e] = 0.f; }
  __syncthreads();

  // ---- gather: 4 lanes per location, bf16x8 channels per lane ----
  const int c4 = lane & 3, l16 = lane >> 2;
  float a[8] = {0.f, 0.f, 0.f, 0.f, 0.f, 0.f, 0.f, 0.f};
  for (int t = 0; t < NT; ++t) {
    const int e = t * 64 + wave * 16 + l16;
    const float wv = wval[e];
    const int loc = wloc[e];
    const bf16x8 qv = *reinterpret_cast<const bf16x8*>(
        qrb + (size_t)loc * CQ + c4 * 8);
#pragma unroll
    for (int j = 0; j < 8; j++)
      a[j] = fmaf(wv, bf2f((unsigned short)qv[j]), a[j]);
  }
#pragma unroll
  for (int o = 4; o < 64; o <<= 1) {
#pragma unroll
    for (int j = 0; j < 8; j++) a[j] += __shfl_xor(a[j], o, 64);
  }
  if (l16 == 0) {
#pragma unroll
    for (int j = 0; j < 8; j++) part[wave][c4 * 8 + j] = a[j];
  }
  __syncthreads();
  if (tid < 32) {
    const float s = part[0][tid] + part[1][tid] + part[2][tid] + part[3][tid];
    out[(size_t)tid * HW + pix] = s * inv;
  }
}

extern "C" void kernel_launch(void* const* d_in, const int* in_sizes, int n_in,
                              void* d_out, int out_size, void* d_ws, size_t ws_size,
                              hipStream_t stream) {
  (void)in_sizes; (void)n_in; (void)out_size; (void)ws_size;
  const float* fr = (const float*)d_in[0];   // feats_r      (3,1,64,48,84)
  const float* ft = (const float*)d_in[1];   // feats_t      (1,64,48,84)
  const float* q  = (const float*)d_in[2];   // quantized_r  (3,1,32,192,336)
  const int* ridx = (const int*)d_in[3];     // ref_index    (3,)
  const int* cur  = (const int*)d_in[4];     // current_ind  (1,)
  float* out = (float*)d_out;

  char* ws = (char*)d_ws;
  float* frT  = (float*)ws;                   ws += (size_t)NREF * HW * C * 4;
  float* ftT  = (float*)ws;                   ws += (size_t)HW * C * 4;
  unsigned short* rbh = (unsigned short*)ws;  ws += (size_t)NREF * HW * C * 2;
  unsigned short* rbl = (unsigned short*)ws;  ws += (size_t)NREF * HW * C * 2;
  unsigned short* tbh = (unsigned short*)ws;  ws += (size_t)HW * C * 2;
  unsigned short* tbl = (unsigned short*)ws;  ws += (size_t)HW * C * 2;
  unsigned short* qrb = (unsigned short*)ws;  ws += (size_t)NREF * HW * CQ * 2;
  float* lg    = (float*)ws;                  ws += (size_t)HW * 512 * 4;
  float* accum = (float*)ws;                  ws += (size_t)NREF * HW * 3 * 4;

  k_prep<<<dim3(HW / 64, 8), dim3(256), 0, stream>>>(fr, ft, q, frT, ftT,
                                                     rbh, rbl, tbh, tbl, qrb, accum);
  k_mfma<<<dim3(6, H, NREF * 7), dim3(256), 0, stream>>>(rbh, rbl, tbh, tbl,
                                                         ridx, cur, accum, lg);
  k_pix<<<dim3(HW), dim3(256), 0, stream>>>(frT, ftT, qrb, lg, accum,
                                            ridx, cur, out);
}